// Round 1
// baseline (175.999 us; speedup 1.0000x reference)
//
#include <hip/hip_runtime.h>

// Problem constants (from reference)
constexpr int BATCH    = 4096;
constexpr int IN_DIM   = 1024;
constexpr int HIDDEN   = 8192;
constexpr int N_LAYERS = 6;
constexpr int OUT_DIM  = 8;
constexpr float INV_TAU = 0.1f;

// Tiling
constexpr int TB   = 4;             // batch rows per workgroup (float4 lanes)
constexpr int NTH  = 1024;          // threads per block (16 waves)
constexpr int NPT  = HIDDEN / NTH;  // neurons per thread = 8 (== OUT_DIM groups)
constexpr int NWAVES = NTH / 64;    // 16

// ---------------------------------------------------------------------------
// Kernel 1: precompute per-neuron gate coefficients c = softmax(w) @ GATE_COEF
// (batch-independent; 6*8192 neurons, 16 weights each) -> d_ws as float4
// ---------------------------------------------------------------------------
__global__ void coef_kernel(const float* __restrict__ logic_w,
                            float4* __restrict__ coef, int n)
{
    int id = blockIdx.x * blockDim.x + threadIdx.x;
    if (id >= n) return;
    const float* w = logic_w + (size_t)id * 16;
    float wv[16];
#pragma unroll
    for (int i = 0; i < 16; ++i) wv[i] = w[i];
    float m = wv[0];
#pragma unroll
    for (int i = 1; i < 16; ++i) m = fmaxf(m, wv[i]);
    float e[16];
    float s = 0.f;
#pragma unroll
    for (int i = 0; i < 16; ++i) { e[i] = expf(wv[i] - m); s += e[i]; }
    float inv = 1.f / s;
    // GATE_COEF columns (16 gates x 4 coefs)
    const float G0[16] = {0,0,0,0,0,0,0,0, 1,1,1,1,1,1,1,1};
    const float G1[16] = {0,0,1,1,0,0,1,1, -1,-1,0,0,-1,-1,0,0};
    const float G2[16] = {0,0,0,0,1,1,1,1, -1,-1,-1,-1,0,0,0,0};
    const float G3[16] = {0,1,-1,0,-1,0,-2,-1, 1,2,0,1,0,1,-1,0};
    float c0 = 0.f, c1 = 0.f, c2 = 0.f, c3 = 0.f;
#pragma unroll
    for (int i = 0; i < 16; ++i) {
        float p = e[i] * inv;
        c0 = fmaf(p, G0[i], c0);
        c1 = fmaf(p, G1[i], c1);
        c2 = fmaf(p, G2[i], c2);
        c3 = fmaf(p, G3[i], c3);
    }
    coef[id] = make_float4(c0, c1, c2, c3);
}

// gate: c0 + c1*a + c2*b + c3*a*b, per batch lane
__device__ __forceinline__ float4 gate4(float4 a, float4 b, float4 c) {
    float4 r;
    r.x = fmaf(c.w, a.x * b.x, fmaf(c.z, b.x, fmaf(c.y, a.x, c.x)));
    r.y = fmaf(c.w, a.y * b.y, fmaf(c.z, b.y, fmaf(c.y, a.y, c.x)));
    r.z = fmaf(c.w, a.z * b.z, fmaf(c.z, b.z, fmaf(c.y, a.z, c.x)));
    r.w = fmaf(c.w, a.w * b.w, fmaf(c.z, b.w, fmaf(c.y, a.w, c.x)));
    return r;
}

// ---------------------------------------------------------------------------
// Kernel 2: whole network fused. One workgroup = TB=4 batch rows; h lives in
// LDS as float4[HIDDEN] (128 KB). All 6 layers in-place (read->barrier->write).
// Epilogue: thread's neuron group k IS output index o; shuffle-reduce.
// ---------------------------------------------------------------------------
__global__ __launch_bounds__(NTH) void net_kernel(
    const float*  __restrict__ x,
    const float4* __restrict__ coef,
    const int*    __restrict__ idx0_a, const int* __restrict__ idx0_b,
    const int*    __restrict__ idx_a,  const int* __restrict__ idx_b,
    const float*  __restrict__ scaler_w, const float* __restrict__ scaler_b,
    float* __restrict__ out)
{
    __shared__ float4 h[HIDDEN];            // 128 KB: h[j] = 4 batch rows
    __shared__ float4 hx[IN_DIM];           // 16 KB : binarized input
    __shared__ float  partials[NWAVES][OUT_DIM][TB]; // 2 KB
    __shared__ float  vals[TB][OUT_DIM];    // 128 B

    const int tid = threadIdx.x;
    const int b0  = blockIdx.x * TB;

    // Load + binarize input tile (NTH == IN_DIM: one column per thread)
    {
        float4 xv;
        xv.x = (x[(size_t)(b0 + 0) * IN_DIM + tid] > 0.5f) ? 1.f : 0.f;
        xv.y = (x[(size_t)(b0 + 1) * IN_DIM + tid] > 0.5f) ? 1.f : 0.f;
        xv.z = (x[(size_t)(b0 + 2) * IN_DIM + tid] > 0.5f) ? 1.f : 0.f;
        xv.w = (x[(size_t)(b0 + 3) * IN_DIM + tid] > 0.5f) ? 1.f : 0.f;
        hx[tid] = xv;
    }
    __syncthreads();

    float4 acc[NPT];

    // Layer 0: gather from hx (IN_DIM), write h (HIDDEN) — disjoint regions
#pragma unroll
    for (int k = 0; k < NPT; ++k) {
        int j = k * NTH + tid;
        float4 a = hx[idx0_a[j]];
        float4 b = hx[idx0_b[j]];
        float4 c = coef[j];
        acc[k] = gate4(a, b, c);
    }
#pragma unroll
    for (int k = 0; k < NPT; ++k) h[k * NTH + tid] = acc[k];
    __syncthreads();

    // Layers 1..5: in-place on h. Reads complete (registers) before writes.
    for (int l = 1; l < N_LAYERS; ++l) {
        const int*    ja = idx_a + (size_t)(l - 1) * HIDDEN;
        const int*    jb = idx_b + (size_t)(l - 1) * HIDDEN;
        const float4* cf = coef  + (size_t)l * HIDDEN;
#pragma unroll
        for (int k = 0; k < NPT; ++k) {
            int j = k * NTH + tid;
            float4 a = h[ja[j]];
            float4 b = h[jb[j]];
            float4 c = cf[j];
            acc[k] = gate4(a, b, c);
        }
        __syncthreads();                    // all reads of h done
        if (l != N_LAYERS - 1) {            // last layer stays in registers
#pragma unroll
            for (int k = 0; k < NPT; ++k) h[k * NTH + tid] = acc[k];
            __syncthreads();
        }
    }

    // Epilogue: neuron j = k*1024 + tid belongs to output group o = k.
    // Reduce acc[k] over the block -> values[t][k], then tiny scaler GEMV.
    const int lane = tid & 63;
    const int wv   = tid >> 6;
#pragma unroll
    for (int k = 0; k < NPT; ++k) {
        float4 v = acc[k];
#pragma unroll
        for (int off = 32; off > 0; off >>= 1) {
            v.x += __shfl_down(v.x, off);
            v.y += __shfl_down(v.y, off);
            v.z += __shfl_down(v.z, off);
            v.w += __shfl_down(v.w, off);
        }
        if (lane == 0) {
            partials[wv][k][0] = v.x;
            partials[wv][k][1] = v.y;
            partials[wv][k][2] = v.z;
            partials[wv][k][3] = v.w;
        }
    }
    __syncthreads();
    if (tid < TB * OUT_DIM) {               // 32 threads finish
        int t  = tid >> 3;                  // batch row in tile
        int oo = tid & 7;                   // output index
        float s = 0.f;
#pragma unroll
        for (int w2 = 0; w2 < NWAVES; ++w2) s += partials[w2][oo][t];
        vals[t][oo] = s * INV_TAU;
    }
    __syncthreads();
    if (tid < TB * OUT_DIM) {
        int t  = tid >> 3;
        int oo = tid & 7;
        float q = scaler_b[oo];
#pragma unroll
        for (int o2 = 0; o2 < OUT_DIM; ++o2)
            q = fmaf(vals[t][o2], scaler_w[oo * OUT_DIM + o2], q);
        out[(size_t)(b0 + t) * OUT_DIM + oo] = q;
    }
}

extern "C" void kernel_launch(void* const* d_in, const int* in_sizes, int n_in,
                              void* d_out, int out_size, void* d_ws, size_t ws_size,
                              hipStream_t stream)
{
    const float* x        = (const float*)d_in[0];
    const float* logic_w  = (const float*)d_in[1];
    const float* scaler_w = (const float*)d_in[2];
    const float* scaler_b = (const float*)d_in[3];
    const int*   idx0_a   = (const int*)d_in[4];
    const int*   idx0_b   = (const int*)d_in[5];
    const int*   idx_a    = (const int*)d_in[6];
    const int*   idx_b    = (const int*)d_in[7];
    float*  out  = (float*)d_out;
    float4* coef = (float4*)d_ws;           // 6*8192*16 B = 768 KB scratch

    const int n = N_LAYERS * HIDDEN;
    coef_kernel<<<(n + 255) / 256, 256, 0, stream>>>(logic_w, coef, n);
    net_kernel<<<BATCH / TB, NTH, 0, stream>>>(x, coef, idx0_a, idx0_b,
                                               idx_a, idx_b, scaler_w, scaler_b, out);
}